// Round 5
// baseline (698.762 us; speedup 1.0000x reference)
//
#include <hip/hip_runtime.h>

#define B_ 4096
#define S_ 2048
#define CH 16         // steps per pipeline chunk (ring depth)

typedef float v2f __attribute__((ext_vector_type(2)));

__device__ __forceinline__ float rcp_(float x)  { return __builtin_amdgcn_rcpf(x); }
__device__ __forceinline__ float exp2_(float x) { return __builtin_amdgcn_exp2f(x); }
// tanh(x)=1-2/(1+2^(2x*log2e)) — saturates clean (rcp(inf)=0), no NaN for huge |x|
__device__ __forceinline__ float tanh_(float x) {
    return fmaf(-2.0f, rcp_(1.0f + exp2_(2.88539008f * x)), 1.0f);
}
// DPP cross-lane (VALU ~2cyc). row_ror:n = 0x120+n (within 16-lane rows).
template<int CTRL>
__device__ __forceinline__ float dppf(float x) {
    int v = __builtin_bit_cast(int, x);
    return __builtin_bit_cast(float,
        __builtin_amdgcn_update_dpp(v, v, CTRL, 0xF, 0xF, false));
}
__device__ __forceinline__ int dppi_ror2(int x) {
    return __builtin_amdgcn_update_dpp(x, x, 0x122, 0xF, 0xF, false);
}
__device__ __forceinline__ void ld8(const float* p, float* o) {
    float4 a = *(const float4*)p;
    float4 b = *(const float4*)(p + 4);
    o[0] = a.x; o[1] = a.y; o[2] = a.z; o[3] = a.w;
    o[4] = b.x; o[5] = b.y; o[6] = b.z; o[7] = b.w;
}

#define L2E 1.44269504f

// 12 waves/block, 16 sequences/block, 8 lanes/sequence.
// Lane layout: two sequences pair-interleaved per 16-lane DPP row
//   (lane = row*16 + j*2 + parity) so row_ror:2q rotates h within a sequence.
// Each lane owns all 4 gates (i,f | g,o) of its h-row as two packed v2f.
//
// ROLE BALANCE ACROSS SIMDs (round-3 verified): heavy waves wv%3==0 ->
// each SIMD gets exactly {1 heavy + 2 light} under both placement policies.
//   wv0: L0 rec seqs 0-7   wv3: L0 rec seqs 8-15
//   wv6: L1 rec seqs 0-7   wv9: L1 rec seqs 8-15  (+heads)
//   wv1,2 / wv4,5:  L0 input-gate producers (grpA / grpB, 8 steps each)
//   wv7,8 / wv10,11: L1 input-gate producers (from ring0)
//
// ROUND-5: no per-iter __syncthreads. Point-to-point LDS counters per
// 8-seq group (seqlock: fence + monotonic chunk count, s_sleep poll).
// Each group runs to ITS OWN max length; waves free-run against true deps
// only; setprio(1) heavies take issue slots from spinning producers.
// Ring safety: 2-deep rings, producer of chunk k waits consumer-ack >= k-1.
__global__ __launch_bounds__(768) void lstm_main(
    const float* __restrict__ seq, const int* __restrict__ lengths,
    const float* __restrict__ Wih0, const float* __restrict__ Whh0,
    const float* __restrict__ bih0, const float* __restrict__ bhh0,
    const float* __restrict__ Wih1, const float* __restrict__ Whh1,
    const float* __restrict__ bih1, const float* __restrict__ bhh1,
    const float* __restrict__ Wl, const float* __restrict__ bl,
    const float* __restrict__ Wv, const float* __restrict__ bv,
    const float* __restrict__ Wa, const float* __restrict__ ba,
    const float* __restrict__ lstd, float* __restrict__ out)
{
    __shared__ float  ring0[2][CH][128];       // h0[seq*8 + j]           16 KiB
    __shared__ float4 ringX[2][CH][16][8];     // L0 input gates          64 KiB
    __shared__ float4 ringY[2][CH][16][8];     // L1 input gates          64 KiB
    // per-group counters: 0 px0, 1 px1, 2 xread, 3 h0w, 4 r0a, 5 r0b,
    //                     6 py0, 7 py1, 8 yread
    volatile __shared__ int ctr[2][9];

    const int tid = threadIdx.x;
    const int wv  = tid >> 6;                  // 0..11
    const int l   = tid & 63;
    const int p   = l & 1;                     // seq parity within 16-lane row
    const int j   = (l >> 1) & 7;              // h-row index
    const int s8  = (l >> 4) * 2 + p;          // 0..7 local sequence in wave

    {
        volatile int* cf = &ctr[0][0];
        if (tid < 18) cf[tid] = 0;
    }
    __syncthreads();                           // the ONLY barrier

    const bool heavy = (wv % 3) == 0;
    int layer, sbase, s0 = 0, ph = 0;
    if (heavy) {
        const int hid = wv / 3;                // 0..3
        layer = hid >> 1;
        sbase = (hid & 1) * 8;
    } else {
        layer = (wv >= 7) ? 1 : 0;
        const int idx = (layer == 0) ? ((wv >= 4) ? (wv - 2) : (wv - 1))
                                     : ((wv >= 10) ? (wv - 8) : (wv - 7));
        sbase = (idx >> 1) * 8;
        ph    = idx & 1;                       // producer half id
        s0    = ph * 8;                        // producer half-chunk (8 steps)
    }
    const int sq = sbase + s8;                 // 0..15 sequence within block
    const int g  = sbase >> 3;                 // group 0/1
    const int b  = blockIdx.x * 16 + sq;

    // DPP ror2 direction probe (setup-only)
    const int probe = dppi_ror2(j);
    const int delta = (j - probe) & 7;

    // gate rows: i=j, f=8+j (sigmoid, scale -log2e); g=16+j (tanh, +2log2e);
    // o=24+j (sigmoid, -log2e)
    v2f wA[8], wB[8];
    v2f biasA = (v2f){0.0f, 0.0f}, biasB = (v2f){0.0f, 0.0f};
    if (heavy) {
        const float* Whh = layer ? Whh1 : Whh0;    // rotated + scaled, no bias
        int idx = j;
        #pragma unroll
        for (int k = 0; k < 8; ++k) {
            wA[k] = (v2f){ Whh[(j)      * 8 + idx] * -L2E,
                           Whh[(8 + j)  * 8 + idx] * -L2E };
            wB[k] = (v2f){ Whh[(16 + j) * 8 + idx] * (2.0f * L2E),
                           Whh[(24 + j) * 8 + idx] * -L2E };
            idx = (idx - delta) & 7;
        }
    } else {
        const float* Wih = layer ? Wih1 : Wih0;    // natural + scaled, bias folded
        const float* bi  = layer ? bih1 : bih0;
        const float* bh  = layer ? bhh1 : bhh0;
        #pragma unroll
        for (int k = 0; k < 8; ++k) {
            wA[k] = (v2f){ Wih[(j)      * 8 + k] * -L2E,
                           Wih[(8 + j)  * 8 + k] * -L2E };
            wB[k] = (v2f){ Wih[(16 + j) * 8 + k] * (2.0f * L2E),
                           Wih[(24 + j) * 8 + k] * -L2E };
        }
        biasA = (v2f){ (bi[j]      + bh[j])      * -L2E,
                       (bi[8 + j]  + bh[8 + j])  * -L2E };
        biasB = (v2f){ (bi[16 + j] + bh[16 + j]) * (2.0f * L2E),
                       (bi[24 + j] + bh[24 + j]) * -L2E };
    }

    // per-GROUP max length: the wave's 8 seqs == its group's 8 seqs for all
    // six waves of the group (lanes differ in bits {0,4,5} == sq bits)
    int m = lengths[b];
    m = max(m, __shfl_xor(m, 1));
    m = max(m, __shfl_xor(m, 16));
    m = max(m, __shfl_xor(m, 32));
    const int nchw  = (m + CH - 1) / CH;       // group-local chunk count
    const int lenm1 = lengths[b] - 1;          // used by L1 heavy only

    float hq = 0.0f, cq = 0.0f, ysave = 0.0f;
    const float* xbase = seq + (size_t)b * S_ * 8;

    // seqlock helpers: waitge = poll until counter >= want, then LDS fence.
    // post-pattern = fence (orders this wave's prior ds ops) + lane0 store.
    auto waitge = [&](int idx, int want) {
        while (ctr[g][idx] < want) __builtin_amdgcn_s_sleep(2);
        __threadfence_block();
    };

    if (heavy) __builtin_amdgcn_s_setprio(1);  // serial chain wins issue arb

    // Heavy-wave step: 7 independent row_ror:2q rotations + split 4+4 tree;
    // Montgomery batched inverse (1 rcp for 3 sigmoids + i*g); saturating
    // tanh for c (c can grow over long sequences).
    auto rstep = [&](v2f aA, v2f aB) {
        const float r0 = hq;
        const float r1 = dppf<0x122>(hq);
        const float r2 = dppf<0x124>(hq);
        const float r3 = dppf<0x126>(hq);
        const float r4 = dppf<0x128>(hq);
        const float r5 = dppf<0x12A>(hq);
        const float r6 = dppf<0x12C>(hq);
        const float r7 = dppf<0x12E>(hq);
        v2f aA1, aB1;
        aA  += wA[0] * (v2f){r0, r0};
        aB  += wB[0] * (v2f){r0, r0};
        aA1  = wA[4] * (v2f){r4, r4};
        aB1  = wB[4] * (v2f){r4, r4};
        aA  += wA[1] * (v2f){r1, r1};
        aB  += wB[1] * (v2f){r1, r1};
        aA1 += wA[5] * (v2f){r5, r5};
        aB1 += wB[5] * (v2f){r5, r5};
        aA  += wA[2] * (v2f){r2, r2};
        aB  += wB[2] * (v2f){r2, r2};
        aA1 += wA[6] * (v2f){r6, r6};
        aB1 += wB[6] * (v2f){r6, r6};
        aA  += wA[3] * (v2f){r3, r3};
        aB  += wB[3] * (v2f){r3, r3};
        aA1 += wA[7] * (v2f){r7, r7};
        aB1 += wB[7] * (v2f){r7, r7};
        aA += aA1; aB += aB1;
        float Ei = exp2_(aA.x), Ef = exp2_(aA.y);
        float Eg = exp2_(aB.x), Eo = exp2_(aB.y);
        float pi = 1.0f + Ei, pf = 1.0f + Ef;
        float pg = 1.0f + Eg, po = 1.0f + Eo;
        float P  = pi * pg;
        float T  = P * pf;
        float R  = rcp_(T * po);               // 1/(pi*pf*pg*po)
        float sf  = (R * P) * po;              // 1/pf
        float itg = ((Eg - 1.0f) * (R * pf)) * po;  // tanh(g)*sigmoid(i)
        cq = fmaf(sf, cq, itg);
        float so = R * T;                      // 1/po
        hq = so * tanh_(cq);
    };

    if (!heavy && layer == 0) {
        // ---- L0 input-gate producer (8 steps/chunk, half ph) ----
        for (int k = 0; k < nchw; ++k) {
            waitge(2, k - 1);                  // slot k&1 free (H0 read k-2)
            const int t0 = k * CH + s0;        // t0+7 <= nchw*CH-1 <= 2047
            float xv[8][8];
            #pragma unroll
            for (int s = 0; s < 8; ++s)
                ld8(xbase + (size_t)(t0 + s) * 8, xv[s]);
            #pragma unroll
            for (int s = 0; s < 8; ++s) {
                v2f aA = biasA, aB = biasB;
                #pragma unroll
                for (int q = 0; q < 8; ++q) {
                    aA += wA[q] * (v2f){xv[s][q], xv[s][q]};
                    aB += wB[q] * (v2f){xv[s][q], xv[s][q]};
                }
                ringX[k & 1][s0 + s][sq][j] = make_float4(aA.x, aA.y, aB.x, aB.y);
            }
            __threadfence_block();
            if (l == 0) ctr[g][ph] = k + 1;    // px_ph
        }
    } else if (!heavy) {
        // ---- L1 input-gate producer (reads ring0, half ph) ----
        for (int n = 0; n < nchw; ++n) {
            waitge(3, n + 1);                  // ring0 chunk n ready
            waitge(8, n - 1);                  // ringY slot n&1 free
            #pragma unroll
            for (int s = 0; s < 8; ++s) {
                const float4 ha = *(const float4*)&ring0[n & 1][s0 + s][sq * 8];
                const float4 hb = *(const float4*)&ring0[n & 1][s0 + s][sq * 8 + 4];
                float hv[8] = {ha.x, ha.y, ha.z, ha.w, hb.x, hb.y, hb.z, hb.w};
                v2f aA = biasA, aB = biasB;
                #pragma unroll
                for (int q = 0; q < 8; ++q) {
                    aA += wA[q] * (v2f){hv[q], hv[q]};
                    aB += wB[q] * (v2f){hv[q], hv[q]};
                }
                ringY[n & 1][s0 + s][sq][j] = make_float4(aA.x, aA.y, aB.x, aB.y);
            }
            __threadfence_block();
            if (l == 0) { ctr[g][4 + ph] = n + 1;   // r0 ack
                          ctr[g][6 + ph] = n + 1; } // py_ph
        }
    } else if (layer == 0) {
        // ---- L0 recurrence ----
        for (int c = 0; c < nchw; ++c) {
            waitge(0, c + 1);                  // both producer halves done
            waitge(1, c + 1);
            float4 xg[CH];
            #pragma unroll
            for (int s = 0; s < CH; ++s) xg[s] = ringX[c & 1][s][sq][j];
            __threadfence_block();             // xg landed in regs
            if (l == 0) ctr[g][2] = c + 1;     // release ringX slot
            waitge(4, c - 1);                  // ring0 slot free (P1 halves)
            waitge(5, c - 1);
            float* r0p = &ring0[c & 1][0][sq * 8 + j];
            #pragma unroll
            for (int s = 0; s < CH; ++s) {
                rstep((v2f){xg[s].x, xg[s].y}, (v2f){xg[s].z, xg[s].w});
                r0p[s * 128] = hq;
            }
            __threadfence_block();
            if (l == 0) ctr[g][3] = c + 1;     // h0w
        }
    } else {
        // ---- L1 recurrence ----
        for (int c = 0; c < nchw; ++c) {
            waitge(6, c + 1);
            waitge(7, c + 1);
            float4 yg[CH];
            #pragma unroll
            for (int s = 0; s < CH; ++s) yg[s] = ringY[c & 1][s][sq][j];
            __threadfence_block();
            if (l == 0) ctr[g][8] = c + 1;     // release ringY slot
            const int u0 = c * CH;
            #pragma unroll
            for (int s = 0; s < CH; ++s) {
                rstep((v2f){yg[s].x, yg[s].y}, (v2f){yg[s].z, yg[s].w});
                ysave = (u0 + s == lenm1) ? hq : ysave;
            }
        }
        // ---- fused heads (each L1-rec wave handles its 8 seqs) ----
        const int lbase = (l & 48) | p;        // lane of (s8, j=0)
        float yv[8];
        #pragma unroll
        for (int k = 0; k < 8; ++k) yv[k] = __shfl(ysave, lbase + 2 * k);
        if (j == 0) {
            float feat[4];
            #pragma unroll
            for (int q = 0; q < 4; ++q) {
                float acc = bl[q];
                #pragma unroll
                for (int k = 0; k < 8; ++k) acc = fmaf(Wl[q * 8 + k], yv[k], acc);
                feat[q] = tanh_(acc);
            }
            float val = bv[0];
            #pragma unroll
            for (int q = 0; q < 4; ++q) val = fmaf(Wv[q], feat[q], val);
            out[b] = val;                                          // value
            #pragma unroll
            for (int a = 0; a < 4; ++a) {
                float am = ba[a];
                #pragma unroll
                for (int q = 0; q < 4; ++q) am = fmaf(Wa[a * 4 + q], feat[q], am);
                out[4096  + b * 4 + a] = am;                       // action_mean
                float ls = lstd[a];
                out[20480 + b * 4 + a] = ls;                       // action_log_std
                out[36864 + b * 4 + a] = exp2_(L2E * ls);          // action_std
            }
        }
    }
}

extern "C" void kernel_launch(void* const* d_in, const int* in_sizes, int n_in,
                              void* d_out, int out_size, void* d_ws, size_t ws_size,
                              hipStream_t stream)
{
    const float* seq   = (const float*)d_in[0];
    const int* lengths = (const int*)d_in[1];
    const float* Wih0  = (const float*)d_in[2];
    const float* Whh0  = (const float*)d_in[3];
    const float* bih0  = (const float*)d_in[4];
    const float* bhh0  = (const float*)d_in[5];
    const float* Wih1  = (const float*)d_in[6];
    const float* Whh1  = (const float*)d_in[7];
    const float* bih1  = (const float*)d_in[8];
    const float* bhh1  = (const float*)d_in[9];
    const float* Wl    = (const float*)d_in[10];
    const float* bl    = (const float*)d_in[11];
    const float* Wv    = (const float*)d_in[12];
    const float* bv    = (const float*)d_in[13];
    const float* Wa    = (const float*)d_in[14];
    const float* ba    = (const float*)d_in[15];
    const float* lstd  = (const float*)d_in[16];

    lstm_main<<<B_ / 16, 768, 0, stream>>>(seq, lengths, Wih0, Whh0, bih0, bhh0,
                                           Wih1, Whh1, bih1, bhh1,
                                           Wl, bl, Wv, bv, Wa, ba, lstd,
                                           (float*)d_out);
}

// Round 7
// 646.657 us; speedup vs baseline: 1.0806x; 1.0806x over previous
//
#include <hip/hip_runtime.h>

#define B_ 4096
#define S_ 2048
#define CH 16         // steps per pipeline chunk (ring depth)

typedef float v2f __attribute__((ext_vector_type(2)));

__device__ __forceinline__ float rcp_(float x)  { return __builtin_amdgcn_rcpf(x); }
__device__ __forceinline__ float exp2_(float x) { return __builtin_amdgcn_exp2f(x); }
// tanh(x)=1-2/(1+2^(2x*log2e)) — saturates clean (rcp(inf)=0), no NaN for huge |x|
__device__ __forceinline__ float tanh_(float x) {
    return fmaf(-2.0f, rcp_(1.0f + exp2_(2.88539008f * x)), 1.0f);
}
// DPP cross-lane (VALU ~2cyc). row_ror:n = 0x120+n (within 16-lane rows).
template<int CTRL>
__device__ __forceinline__ float dppf(float x) {
    int v = __builtin_bit_cast(int, x);
    return __builtin_bit_cast(float,
        __builtin_amdgcn_update_dpp(v, v, CTRL, 0xF, 0xF, false));
}
__device__ __forceinline__ int dppi_ror2(int x) {
    return __builtin_amdgcn_update_dpp(x, x, 0x122, 0xF, 0xF, false);
}

// ---- guaranteed packed fp32 math (VOP3P). op_sel_hi broadcast: the scalar
// multiplier lives in one half of a pair; both result halves read that half.
// Modifier arrays are [src0, src1, src2] = [w, x, acc].
// acc += w * bcast(x.lo)
__device__ __forceinline__ v2f pk_fma_blo(v2f acc, v2f w, v2f x) {
    v2f d;
    asm("v_pk_fma_f32 %0, %1, %2, %3 op_sel_hi:[1,0,1]"
        : "=v"(d) : "v"(w), "v"(x), "v"(acc));
    return d;
}
// acc += w * bcast(x.hi)
__device__ __forceinline__ v2f pk_fma_bhi(v2f acc, v2f w, v2f x) {
    v2f d;
    asm("v_pk_fma_f32 %0, %1, %2, %3 op_sel:[0,1,0] op_sel_hi:[1,1,1]"
        : "=v"(d) : "v"(w), "v"(x), "v"(acc));
    return d;
}
// w * bcast(x.lo)
__device__ __forceinline__ v2f pk_mul_blo(v2f w, v2f x) {
    v2f d;
    asm("v_pk_mul_f32 %0, %1, %2 op_sel_hi:[1,0]"
        : "=v"(d) : "v"(w), "v"(x));
    return d;
}

#define L2E 1.44269504f

// 12 waves/block, 16 sequences/block, 8 lanes/sequence.
// Lane layout: two sequences pair-interleaved per 16-lane DPP row
//   (lane = row*16 + j*2 + parity) so row_ror:2q rotates h within a sequence.
// Each lane owns all 4 gates (i,f | g,o) of its h-row as two packed v2f.
//
// ROLE BALANCE ACROSS SIMDs (round-3 verified): heavy waves wv%3==0 ->
// each SIMD gets exactly {1 heavy + 2 light} under both placement policies.
// ROUND-6: all dot products via inline-asm v_pk_fma_f32 with op_sel_hi
// broadcast (no scalarization, no broadcast movs). FP order identical to
// round-4 -> bitwise-same results. Barrier structure = round-4 (best).
// Grid = 256 blocks = 1/CU, 12 waves/CU = 3/SIMD.
__global__ __launch_bounds__(768) void lstm_main(
    const float* __restrict__ seq, const int* __restrict__ lengths,
    const float* __restrict__ Wih0, const float* __restrict__ Whh0,
    const float* __restrict__ bih0, const float* __restrict__ bhh0,
    const float* __restrict__ Wih1, const float* __restrict__ Whh1,
    const float* __restrict__ bih1, const float* __restrict__ bhh1,
    const float* __restrict__ Wl, const float* __restrict__ bl,
    const float* __restrict__ Wv, const float* __restrict__ bv,
    const float* __restrict__ Wa, const float* __restrict__ ba,
    const float* __restrict__ lstd, float* __restrict__ out)
{
    __shared__ float  ring0[2][CH][128];       // h0[seq*8 + j]           16 KiB
    __shared__ float4 ringX[2][CH][16][8];     // L0 input gates          64 KiB
    __shared__ float4 ringY[2][CH][16][8];     // L1 input gates          64 KiB

    const int tid = threadIdx.x;
    const int wv  = tid >> 6;                  // 0..11
    const int l   = tid & 63;
    const int p   = l & 1;                     // seq parity within 16-lane row
    const int j   = (l >> 1) & 7;              // h-row index
    const int s8  = (l >> 4) * 2 + p;          // 0..7 local sequence in wave

    const bool heavy = (wv % 3) == 0;
    int layer, sbase, s0 = 0;
    if (heavy) {
        const int hid = wv / 3;                // 0..3
        layer = hid >> 1;
        sbase = (hid & 1) * 8;
    } else {
        layer = (wv >= 7) ? 1 : 0;
        const int idx = (layer == 0) ? ((wv >= 4) ? (wv - 2) : (wv - 1))
                                     : ((wv >= 10) ? (wv - 8) : (wv - 7));
        sbase = (idx >> 1) * 8;
        s0    = (idx & 1) * 8;                 // producer half-chunk (8 steps)
    }
    const int sq = sbase + s8;                 // 0..15 sequence within block
    const int b  = blockIdx.x * 16 + sq;

    // DPP ror2 direction probe (setup-only)
    const int probe = dppi_ror2(j);
    const int delta = (j - probe) & 7;

    // gate rows: i=j, f=8+j (sigmoid, scale -log2e); g=16+j (tanh, +2log2e);
    // o=24+j (sigmoid, -log2e)
    v2f wA[8], wB[8];
    v2f biasA = (v2f){0.0f, 0.0f}, biasB = (v2f){0.0f, 0.0f};
    if (heavy) {
        const float* Whh = layer ? Whh1 : Whh0;    // rotated + scaled, no bias
        int idx = j;
        #pragma unroll
        for (int k = 0; k < 8; ++k) {
            wA[k] = (v2f){ Whh[(j)      * 8 + idx] * -L2E,
                           Whh[(8 + j)  * 8 + idx] * -L2E };
            wB[k] = (v2f){ Whh[(16 + j) * 8 + idx] * (2.0f * L2E),
                           Whh[(24 + j) * 8 + idx] * -L2E };
            idx = (idx - delta) & 7;
        }
    } else {
        const float* Wih = layer ? Wih1 : Wih0;    // natural + scaled, bias folded
        const float* bi  = layer ? bih1 : bih0;
        const float* bh  = layer ? bhh1 : bhh0;
        #pragma unroll
        for (int k = 0; k < 8; ++k) {
            wA[k] = (v2f){ Wih[(j)      * 8 + k] * -L2E,
                           Wih[(8 + j)  * 8 + k] * -L2E };
            wB[k] = (v2f){ Wih[(16 + j) * 8 + k] * (2.0f * L2E),
                           Wih[(24 + j) * 8 + k] * -L2E };
        }
        biasA = (v2f){ (bi[j]      + bh[j])      * -L2E,
                       (bi[8 + j]  + bh[8 + j])  * -L2E };
        biasB = (v2f){ (bi[16 + j] + bh[16 + j]) * (2.0f * L2E),
                       (bi[24 + j] + bh[24 + j]) * -L2E };
    }

    // block-uniform max length over the 16 sequences (lanes 0-15 cover all)
    int m = lengths[blockIdx.x * 16 + (l & 15)];
    m = max(m, __shfl_xor(m, 1));
    m = max(m, __shfl_xor(m, 2));
    m = max(m, __shfl_xor(m, 4));
    m = max(m, __shfl_xor(m, 8));
    const int nch   = (m + CH - 1) / CH;
    const int lenm1 = lengths[b] - 1;          // used by L1 heavy only

    float hq = 0.0f, cq = 0.0f, ysave = 0.0f;
    const float* xbase = seq + (size_t)b * S_ * 8;

    if (heavy) __builtin_amdgcn_s_setprio(1);  // serial chain wins issue arb

    // Heavy-wave step: rotation PAIRS {r2q, r2q+1} built by 2 dpp each (one
    // mov for r0=hq); 16 pk_fma with op_sel broadcast; split 4+4 tree;
    // Montgomery batched inverse (1 rcp for 3 sigmoids + i*g); saturating
    // tanh for c. FP accumulation order identical to round-4.
    auto rstep = [&](v2f aA, v2f aB) {
        v2f r01, r23, r45, r67;
        r01.x = hq;               r01.y = dppf<0x122>(hq);
        r23.x = dppf<0x124>(hq);  r23.y = dppf<0x126>(hq);
        r45.x = dppf<0x128>(hq);  r45.y = dppf<0x12A>(hq);
        r67.x = dppf<0x12C>(hq);  r67.y = dppf<0x12E>(hq);
        v2f aA1, aB1;
        aA  = pk_fma_blo(aA, wA[0], r01);
        aB  = pk_fma_blo(aB, wB[0], r01);
        aA1 = pk_mul_blo(wA[4], r45);
        aB1 = pk_mul_blo(wB[4], r45);
        aA  = pk_fma_bhi(aA, wA[1], r01);
        aB  = pk_fma_bhi(aB, wB[1], r01);
        aA1 = pk_fma_bhi(aA1, wA[5], r45);
        aB1 = pk_fma_bhi(aB1, wB[5], r45);
        aA  = pk_fma_blo(aA, wA[2], r23);
        aB  = pk_fma_blo(aB, wB[2], r23);
        aA1 = pk_fma_blo(aA1, wA[6], r67);
        aB1 = pk_fma_blo(aB1, wB[6], r67);
        aA  = pk_fma_bhi(aA, wA[3], r23);
        aB  = pk_fma_bhi(aB, wB[3], r23);
        aA1 = pk_fma_bhi(aA1, wA[7], r67);
        aB1 = pk_fma_bhi(aB1, wB[7], r67);
        aA += aA1; aB += aB1;
        float Ei = exp2_(aA.x), Ef = exp2_(aA.y);
        float Eg = exp2_(aB.x), Eo = exp2_(aB.y);
        float pi = 1.0f + Ei, pf = 1.0f + Ef;
        float pg = 1.0f + Eg, po = 1.0f + Eo;
        float P  = pi * pg;
        float T  = P * pf;
        float R  = rcp_(T * po);               // 1/(pi*pf*pg*po)
        float sf  = (R * P) * po;              // 1/pf
        float itg = ((Eg - 1.0f) * (R * pf)) * po;  // tanh(g)*sigmoid(i)
        cq = fmaf(sf, cq, itg);
        float so = R * T;                      // 1/po
        hq = so * tanh_(cq);
    };

    // Producer dot: x/h pairs come straight out of the float4 loads (adjacent
    // regs) — zero broadcast movs with op_sel. Order identical to round-4.
    auto pdot = [&](v2f x01, v2f x23, v2f x45, v2f x67, v2f& aA, v2f& aB) {
        aA = biasA; aB = biasB;
        aA = pk_fma_blo(aA, wA[0], x01); aA = pk_fma_bhi(aA, wA[1], x01);
        aA = pk_fma_blo(aA, wA[2], x23); aA = pk_fma_bhi(aA, wA[3], x23);
        aA = pk_fma_blo(aA, wA[4], x45); aA = pk_fma_bhi(aA, wA[5], x45);
        aA = pk_fma_blo(aA, wA[6], x67); aA = pk_fma_bhi(aA, wA[7], x67);
        aB = pk_fma_blo(aB, wB[0], x01); aB = pk_fma_bhi(aB, wB[1], x01);
        aB = pk_fma_blo(aB, wB[2], x23); aB = pk_fma_bhi(aB, wB[3], x23);
        aB = pk_fma_blo(aB, wB[4], x45); aB = pk_fma_bhi(aB, wB[5], x45);
        aB = pk_fma_blo(aB, wB[6], x67); aB = pk_fma_bhi(aB, wB[7], x67);
    };

    // Pipeline: iter k: L0 producers write chunk k; L0 rec runs k-1;
    // L1 producers write k-2 (from ring0); L1 rec runs k-3.
    // Each ring slot: write@k, read@k+1, rewrite@k+2 — one barrier/iter safe.
    for (int k = 0; k <= nch + 2; ++k) {
        if (!heavy) {
            if (layer == 0) {                    // ---- L0 input gates ----
                if (k < nch) {
                    const int t0 = k * CH + s0;
                    #pragma unroll
                    for (int s = 0; s < 8; ++s) {
                        const float* xp = xbase + (size_t)(t0 + s) * 8;
                        const float4 xa = *(const float4*)xp;
                        const float4 xb = *(const float4*)(xp + 4);
                        v2f aA, aB;
                        pdot((v2f){xa.x, xa.y}, (v2f){xa.z, xa.w},
                             (v2f){xb.x, xb.y}, (v2f){xb.z, xb.w}, aA, aB);
                        ringX[k & 1][s0 + s][sq][j] = make_float4(aA.x, aA.y, aB.x, aB.y);
                    }
                }
            } else {                             // ---- L1 input gates ----
                const int c = k - 2;
                if (c >= 0 && c < nch) {
                    #pragma unroll
                    for (int s = 0; s < 8; ++s) {
                        const float4 ha = *(const float4*)&ring0[c & 1][s0 + s][sq * 8];
                        const float4 hb = *(const float4*)&ring0[c & 1][s0 + s][sq * 8 + 4];
                        v2f aA, aB;
                        pdot((v2f){ha.x, ha.y}, (v2f){ha.z, ha.w},
                             (v2f){hb.x, hb.y}, (v2f){hb.z, hb.w}, aA, aB);
                        ringY[c & 1][s0 + s][sq][j] = make_float4(aA.x, aA.y, aB.x, aB.y);
                    }
                }
            }
        } else if (layer == 0) {                 // ---- L0 recurrence ----
            const int c = k - 1;
            if (c >= 0 && c < nch) {
                float4 xg[CH];
                #pragma unroll
                for (int s = 0; s < CH; ++s) xg[s] = ringX[c & 1][s][sq][j];
                float* r0p = &ring0[c & 1][0][sq * 8 + j];
                #pragma unroll
                for (int s = 0; s < CH; ++s) {
                    rstep((v2f){xg[s].x, xg[s].y}, (v2f){xg[s].z, xg[s].w});
                    r0p[s * 128] = hq;
                }
            }
        } else {                                 // ---- L1 recurrence ----
            const int c = k - 3;
            if (c >= 0 && c < nch) {
                float4 yg[CH];
                #pragma unroll
                for (int s = 0; s < CH; ++s) yg[s] = ringY[c & 1][s][sq][j];
                const int u0 = c * CH;
                #pragma unroll
                for (int s = 0; s < CH; ++s) {
                    rstep((v2f){yg[s].x, yg[s].y}, (v2f){yg[s].z, yg[s].w});
                    ysave = (u0 + s == lenm1) ? hq : ysave;
                }
            }
        }
        __syncthreads();
    }

    if (heavy && layer == 1) {
        // ---- fused heads (each L1-rec wave handles its 8 seqs) ----
        const int lbase = (l & 48) | p;          // lane of (s8, j=0)
        float yv[8];
        #pragma unroll
        for (int k = 0; k < 8; ++k) yv[k] = __shfl(ysave, lbase + 2 * k);
        if (j == 0) {
            float feat[4];
            #pragma unroll
            for (int q = 0; q < 4; ++q) {
                float acc = bl[q];
                #pragma unroll
                for (int k = 0; k < 8; ++k) acc = fmaf(Wl[q * 8 + k], yv[k], acc);
                feat[q] = tanh_(acc);
            }
            float val = bv[0];
            #pragma unroll
            for (int q = 0; q < 4; ++q) val = fmaf(Wv[q], feat[q], val);
            out[b] = val;                                          // value
            #pragma unroll
            for (int a = 0; a < 4; ++a) {
                float am = ba[a];
                #pragma unroll
                for (int q = 0; q < 4; ++q) am = fmaf(Wa[a * 4 + q], feat[q], am);
                out[4096  + b * 4 + a] = am;                       // action_mean
                float ls = lstd[a];
                out[20480 + b * 4 + a] = ls;                       // action_log_std
                out[36864 + b * 4 + a] = exp2_(L2E * ls);          // action_std
            }
        }
    }
}

extern "C" void kernel_launch(void* const* d_in, const int* in_sizes, int n_in,
                              void* d_out, int out_size, void* d_ws, size_t ws_size,
                              hipStream_t stream)
{
    const float* seq   = (const float*)d_in[0];
    const int* lengths = (const int*)d_in[1];
    const float* Wih0  = (const float*)d_in[2];
    const float* Whh0  = (const float*)d_in[3];
    const float* bih0  = (const float*)d_in[4];
    const float* bhh0  = (const float*)d_in[5];
    const float* Wih1  = (const float*)d_in[6];
    const float* Whh1  = (const float*)d_in[7];
    const float* bih1  = (const float*)d_in[8];
    const float* bhh1  = (const float*)d_in[9];
    const float* Wl    = (const float*)d_in[10];
    const float* bl    = (const float*)d_in[11];
    const float* Wv    = (const float*)d_in[12];
    const float* bv    = (const float*)d_in[13];
    const float* Wa    = (const float*)d_in[14];
    const float* ba    = (const float*)d_in[15];
    const float* lstd  = (const float*)d_in[16];

    lstm_main<<<B_ / 16, 768, 0, stream>>>(seq, lengths, Wih0, Whh0, bih0, bhh0,
                                           Wih1, Whh1, bih1, bhh1,
                                           Wl, bl, Wv, bv, Wa, ba, lstd,
                                           (float*)d_out);
}